// Round 4
// baseline (2255.798 us; speedup 1.0000x reference)
//
#include <hip/hip_runtime.h>
#include <stdint.h>

#define B_DIM 8
#define S_DIM 4096
#define F_DIM 512
#define H_DIM 2048
#define W_DIM 16
#define L_DIM 4081               // S - W + 1
#define M_TOT 32648              // B * L
#define K1_DIM 8192              // W * F
#define SXF 2097152              // S * F
#define LT_PER_B 17              // ceil(4081/256) M-tiles per batch

typedef __bf16 bf16x8 __attribute__((ext_vector_type(8)));
typedef float f32x4 __attribute__((ext_vector_type(4)));

__device__ __forceinline__ unsigned short f2bf(float f) {
  union { float f; uint32_t u; } a; a.f = f;
  return (unsigned short)((a.u + 0x7fffu + ((a.u >> 16) & 1u)) >> 16);
}

__device__ __forceinline__ void async16(const void* g, void* l) {
  __builtin_amdgcn_global_load_lds(
      (__attribute__((address_space(1))) void*)(uintptr_t)g,
      (__attribute__((address_space(3))) void*)l, 16, 0, 0);
}

// ---------------- GEMM1: h = relu(x_hankel @ w1 + b1) ----------------------
// K reordered as k = w*512 + f, iterated fs-major (f-slice of 32), w-minor.
// Per sub-iter (fs,w) the A tile is the w-shifted 256-row window of xb at
// f-columns [fs*32, fs*32+32) -- 16 KB -- and B is the matching 32 k-rows of
// the (transposed) w1 column tile -- 16 KB. All A re-reads across the 16 w
// values hit L2 (working set per XCD ~0.5 MB), so staging latency is L2-class
// and the depth-1 double buffer covers it. M-tiles are per-batch (17 tiles of
// 256 per batch) so the shift never crosses a batch boundary.
__global__ __launch_bounds__(512) void gemm1_kernel(
    const unsigned short* __restrict__ xb,
    const unsigned short* __restrict__ w1t,
    const float* __restrict__ bias1,
    unsigned short* __restrict__ h)
{
  __shared__ alignas(16) unsigned short lsA[16384];  // 2 stages x 16 KB
  __shared__ alignas(16) unsigned short lsB[16384];

  const int tid  = threadIdx.x;
  const int lane = tid & 63;
  const int wave = tid >> 6;           // 0..7
  const int id = blockIdx.x;
  const int nt = id & 7;               // XCD-pinned B column
  const int r  = id >> 3;              // 0..135
  const int b  = r / LT_PER_B;         // batch
  const int lt = r - b * LT_PER_B;     // M-tile within batch
  const int l0 = lt * 256;

  // staging decode: chunk c0 = tid (m16=c&15, g=(c>>4)&3, T=c>>6), c1 = tid+512
  const int m16 = tid & 15;
  const int g   = (tid >> 4) & 3;
  const int T0  = tid >> 6;            // 0..7 ; c1 has T0+8

  const int la0 = l0 + T0 * 16 + m16;  // tile-row -> x row (before +w)
  const int la1 = la0 + 128;
  const unsigned short* baseA = xb + (size_t)b * SXF + g * 8;

  const int colB0 = nt * 256 + T0 * 16 + m16;
  const unsigned short* baseB0 = w1t + (size_t)colB0 * K1_DIM + g * 8;
  const unsigned short* baseB1 = baseB0 + (size_t)128 * K1_DIM;

  const int wm = wave >> 1;            // 0..3 : 64-row band
  const int wn = wave & 1;             // 0..1 : 128-col band

  f32x4 acc[4][8] = {};

  // prologue: stage sub-iter 0 (fs=0, w=0) into buffer 0
  {
    int ro0 = la0 > 4095 ? 4095 : la0;
    int ro1 = la1 > 4095 ? 4095 : la1;
    unsigned short* a = lsA + tid * 8;
    unsigned short* bb = lsB + tid * 8;
    async16(baseA + (size_t)ro0 * F_DIM, a);
    async16(baseA + (size_t)ro1 * F_DIM, a + 4096);
    async16(baseB0, bb);
    async16(baseB1, bb + 4096);
  }

  int cbuf = 0;
  for (int s = 0; s < 256; ++s) {      // s = fs*16 + w
    __syncthreads();                   // sub-iter s ready in buf cbuf
    if (s + 1 < 256) {                 // prefetch s+1 into other buffer
      const int sn = s + 1;
      const int w  = sn & 15;
      const int fs = sn >> 4;
      int ro0 = la0 + w; if (ro0 > 4095) ro0 = 4095;
      int ro1 = la1 + w; if (ro1 > 4095) ro1 = 4095;
      const size_t koff = (size_t)(w * 512 + fs * 32);
      unsigned short* a = lsA + (cbuf ^ 1) * 8192 + tid * 8;
      unsigned short* bb = lsB + (cbuf ^ 1) * 8192 + tid * 8;
      async16(baseA + (size_t)ro0 * F_DIM + fs * 32, a);
      async16(baseA + (size_t)ro1 * F_DIM + fs * 32, a + 4096);
      async16(baseB0 + koff, bb);
      async16(baseB1 + koff, bb + 4096);
    }
    const bf16x8* lA = (const bf16x8*)(lsA + cbuf * 8192) + wm * 256 + lane;
    const bf16x8* lB = (const bf16x8*)(lsB + cbuf * 8192) + wn * 512 + lane;
    bf16x8 af[4], bfr[8];
#pragma unroll
    for (int t = 0; t < 4; ++t) af[t] = lA[t * 64];
#pragma unroll
    for (int u = 0; u < 8; ++u) bfr[u] = lB[u * 64];
#pragma unroll
    for (int t = 0; t < 4; ++t)
#pragma unroll
      for (int u = 0; u < 8; ++u)
        acc[t][u] = __builtin_amdgcn_mfma_f32_16x16x32_bf16(af[t], bfr[u], acc[t][u], 0, 0, 0);
    cbuf ^= 1;
  }

  // C/D layout: col = lane&15, row = (lane>>4)*4 + reg
  const int ncol = nt * 256 + wn * 128 + (lane & 15);
  const int lrow = l0 + wm * 64 + (lane >> 4) * 4;
#pragma unroll
  for (int u = 0; u < 8; ++u) {
    const int n = ncol + u * 16;
    const float bv = bias1[n];
#pragma unroll
    for (int t = 0; t < 4; ++t) {
#pragma unroll
      for (int rr = 0; rr < 4; ++rr) {
        const int l = lrow + t * 16 + rr;
        if (l < L_DIM) {
          float v = acc[t][u][rr] + bv;
          v = v > 0.f ? v : 0.f;
          h[(size_t)(b * L_DIM + l) * H_DIM + n] = f2bf(v);
        }
      }
    }
  }
}

// ---------------- GEMM2: y = h @ w2 + b2, fp32 out with Hankel-pad store ----
__global__ __launch_bounds__(512) void gemm2_kernel(
    const unsigned short* __restrict__ hmat,
    const unsigned short* __restrict__ w2t,   // [512][2048]
    const float* __restrict__ bias2,
    float* __restrict__ out)
{
  __shared__ alignas(16) unsigned short lsA[16384];
  __shared__ alignas(16) unsigned short lsB[16384];

  const int tid  = threadIdx.x;
  const int lane = tid & 63;
  const int wave = tid >> 6;
  const int id = blockIdx.x;
  const int nt = id & 1;               // 2 col tiles of 256 (N=512)
  const int mt = id >> 1;

  const int m16 = tid & 15;
  const int g   = (tid >> 4) & 3;
  const int T0  = tid >> 6;

  int rowA0 = mt * 256 + T0 * 16 + m16;
  int rowA1 = rowA0 + 128;
  if (rowA0 >= M_TOT) rowA0 = M_TOT - 1;
  if (rowA1 >= M_TOT) rowA1 = M_TOT - 1;
  const unsigned short* pA0 = hmat + (size_t)rowA0 * H_DIM + g * 8;
  const unsigned short* pA1 = hmat + (size_t)rowA1 * H_DIM + g * 8;

  const int colB0 = nt * 256 + T0 * 16 + m16;
  const unsigned short* pB0 = w2t + (size_t)colB0 * H_DIM + g * 8;
  const unsigned short* pB1 = pB0 + (size_t)128 * H_DIM;

  const int wm = wave >> 1;
  const int wn = wave & 1;

  f32x4 acc[4][8] = {};

  {
    unsigned short* a = lsA + tid * 8;
    unsigned short* bb = lsB + tid * 8;
    async16(pA0, a); async16(pA1, a + 4096);
    async16(pB0, bb); async16(pB1, bb + 4096);
    pA0 += 32; pA1 += 32; pB0 += 32; pB1 += 32;
  }

  int cbuf = 0;
  const int KT = H_DIM / 32;           // 64
  for (int kt = 0; kt < KT; ++kt) {
    __syncthreads();
    if (kt + 1 < KT) {
      unsigned short* a = lsA + (cbuf ^ 1) * 8192 + tid * 8;
      unsigned short* bb = lsB + (cbuf ^ 1) * 8192 + tid * 8;
      async16(pA0, a); async16(pA1, a + 4096);
      async16(pB0, bb); async16(pB1, bb + 4096);
      pA0 += 32; pA1 += 32; pB0 += 32; pB1 += 32;
    }
    const bf16x8* lA = (const bf16x8*)(lsA + cbuf * 8192) + wm * 256 + lane;
    const bf16x8* lB = (const bf16x8*)(lsB + cbuf * 8192) + wn * 512 + lane;
    bf16x8 af[4], bfr[8];
#pragma unroll
    for (int t = 0; t < 4; ++t) af[t] = lA[t * 64];
#pragma unroll
    for (int u = 0; u < 8; ++u) bfr[u] = lB[u * 64];
#pragma unroll
    for (int t = 0; t < 4; ++t)
#pragma unroll
      for (int u = 0; u < 8; ++u)
        acc[t][u] = __builtin_amdgcn_mfma_f32_16x16x32_bf16(af[t], bfr[u], acc[t][u], 0, 0, 0);
    cbuf ^= 1;
  }

  const int ncol = nt * 256 + wn * 128 + (lane & 15);
  const int mrow = mt * 256 + wm * 64 + (lane >> 4) * 4;
#pragma unroll
  for (int u = 0; u < 8; ++u) {
    const int n = ncol + u * 16;
    const float bv = bias2[n];
#pragma unroll
    for (int t = 0; t < 4; ++t) {
#pragma unroll
      for (int rr = 0; rr < 4; ++rr) {
        const int m = mrow + t * 16 + rr;
        if (m < M_TOT) {
          const int bb = m / L_DIM;
          const int l = m - bb * L_DIM;
          out[(size_t)bb * SXF + (size_t)l * F_DIM + n] = acc[t][u][rr] + bv;
        }
      }
    }
  }
}

// ---------------- conversion / transpose / pad helpers ----------------------
__global__ void cvt_bf16_kernel(const float* __restrict__ in,
                                unsigned short* __restrict__ out, int n4) {
  int idx = blockIdx.x * 256 + threadIdx.x;
  if (idx < n4) {
    float4 v = ((const float4*)in)[idx];
    ushort4 o;
    o.x = f2bf(v.x); o.y = f2bf(v.y); o.z = f2bf(v.z); o.w = f2bf(v.w);
    ((ushort4*)out)[idx] = o;
  }
}

// out[c][r] = bf16(in[r][c]); R, C multiples of 64
__global__ void transpose_cvt_kernel(const float* __restrict__ in,
                                     unsigned short* __restrict__ out, int R, int C) {
  __shared__ unsigned short tile[64][72];
  const int tx = threadIdx.x & 15;
  const int ty = threadIdx.x >> 4;
  const int r0 = blockIdx.x * 64;
  const int c0 = blockIdx.y * 64;
#pragma unroll
  for (int i = 0; i < 4; ++i) {
    const int rr = r0 + ty + i * 16;
    float4 v = *(const float4*)(in + (size_t)rr * C + c0 + tx * 4);
    tile[ty + i * 16][tx * 4 + 0] = f2bf(v.x);
    tile[ty + i * 16][tx * 4 + 1] = f2bf(v.y);
    tile[ty + i * 16][tx * 4 + 2] = f2bf(v.z);
    tile[ty + i * 16][tx * 4 + 3] = f2bf(v.w);
  }
  __syncthreads();
#pragma unroll
  for (int i = 0; i < 4; ++i) {
    const int c = c0 + ty + i * 16;
    ushort4 o;
    o.x = tile[tx * 4 + 0][ty + i * 16];
    o.y = tile[tx * 4 + 1][ty + i * 16];
    o.z = tile[tx * 4 + 2][ty + i * 16];
    o.w = tile[tx * 4 + 3][ty + i * 16];
    *(ushort4*)(out + (size_t)c * R + r0 + tx * 4) = o;
  }
}

__global__ void zero_pad_kernel(float* __restrict__ out) {
  int idx = blockIdx.x * 256 + threadIdx.x;          // 8 * 15 * 128 float4s
  if (idx < B_DIM * 15 * 128) {
    int b = idx / (15 * 128);
    int rem = idx - b * (15 * 128);
    int l = L_DIM + rem / 128;
    int f4 = rem - (rem / 128) * 128;
    ((float4*)out)[(size_t)b * (SXF / 4) + (size_t)l * 128 + f4] =
        make_float4(0.f, 0.f, 0.f, 0.f);
  }
}

__global__ void fill_sentinel(float* out, int n) {   // distinctive ws-too-small marker
  int idx = blockIdx.x * 256 + threadIdx.x;
  if (idx < n) out[idx] = 12345.0f;
}

extern "C" void kernel_launch(void* const* d_in, const int* in_sizes, int n_in,
                              void* d_out, int out_size, void* d_ws, size_t ws_size,
                              hipStream_t stream) {
  const float* x  = (const float*)d_in[0];
  const float* w1 = (const float*)d_in[1];
  const float* b1 = (const float*)d_in[2];
  const float* w2 = (const float*)d_in[3];
  const float* b2 = (const float*)d_in[4];
  float* out = (float*)d_out;

  const size_t OFF_H   = 0;                               // 32648*2048*2 = 133726208
  const size_t OFF_XB  = 133726208;                       // 16777216*2   = 33554432
  const size_t OFF_W1T = OFF_XB + 33554432;               // 8192*2048*2  = 33554432
  const size_t OFF_W2T = OFF_W1T + 33554432;              // 2048*512*2   = 2097152
  const size_t WS_NEED = OFF_W2T + 2097152;               // ~202.9 MB

  if (ws_size < WS_NEED) {
    fill_sentinel<<<65536, 256, 0, stream>>>(out, out_size);
    return;
  }

  unsigned short* hbuf = (unsigned short*)((char*)d_ws + OFF_H);
  unsigned short* xb   = (unsigned short*)((char*)d_ws + OFF_XB);
  unsigned short* w1t  = (unsigned short*)((char*)d_ws + OFF_W1T);
  unsigned short* w2t  = (unsigned short*)((char*)d_ws + OFF_W2T);

  cvt_bf16_kernel<<<16384, 256, 0, stream>>>(x, xb, 4194304);
  transpose_cvt_kernel<<<dim3(128, 32), 256, 0, stream>>>(w1, w1t, 8192, 2048);
  transpose_cvt_kernel<<<dim3(32, 8), 256, 0, stream>>>(w2, w2t, 2048, 512);
  gemm1_kernel<<<1088, 512, 0, stream>>>(xb, w1t, b1, hbuf);
  gemm2_kernel<<<256, 512, 0, stream>>>(hbuf, w2t, b2, out);
  zero_pad_kernel<<<60, 256, 0, stream>>>(out);
}